// Round 1
// baseline (79.443 us; speedup 1.0000x reference)
//
#include <hip/hip_runtime.h>

// SLayer RBF pooling: out[b,n] = sum_p mask[b,p] * exp(-(s0*(c0-x0)^2 + s1*(c1-x1)^2))
// B=64, P=16384, N=64, D=2.
//
// Structure: lane = center index n (one accumulator per lane). Points staged in
// LDS via coalesced float4 loads; inner-loop LDS reads are wave-uniform
// broadcasts (conflict-free). exp(-e) computed as exp2(t) with -log2(e) folded
// into per-n coefficients: t = A + x0*(C0*x0+B0) + x1*(C1*x1+B1)  (4 FMAs).

#if __has_builtin(__builtin_amdgcn_exp2f)
#define EXP2(x) __builtin_amdgcn_exp2f(x)
#else
#define EXP2(x) exp2f(x)
#endif

constexpr int BATCH  = 64;
constexpr int P      = 16384;
constexpr int N      = 64;
constexpr int CHUNKS = 16;            // point-chunks per batch
constexpr int CHUNK  = P / CHUNKS;    // 1024 points per block
constexpr int BLOCK  = 256;           // 4 waves
constexpr int WPTS   = CHUNK / 4;     // 256 points per wave

__global__ __launch_bounds__(BLOCK) void slayer_rbf(
    const float* __restrict__ batch,
    const float* __restrict__ mask,
    const float* __restrict__ centers,
    const float* __restrict__ sharp,
    float* __restrict__ out)
{
    __shared__ float sx0[CHUNK];
    __shared__ float sx1[CHUNK];
    __shared__ float smk[CHUNK];
    __shared__ float red[4][N];

    const int blk   = blockIdx.x;
    const int b     = blk >> 4;              // / CHUNKS
    const int chunk = blk & (CHUNKS - 1);
    const int tid   = threadIdx.x;

    // ---- stage batch chunk into LDS (SoA), coalesced float4 loads ----
    // batch layout: [B][P][2] interleaved x0,x1
    const float4* bp = (const float4*)(batch + ((size_t)b * P + (size_t)chunk * CHUNK) * 2);
    #pragma unroll
    for (int i = tid; i < CHUNK / 2; i += BLOCK) {   // 512 float4 = 2048 floats
        float4 v = bp[i];
        sx0[2 * i]     = v.x; sx1[2 * i]     = v.y;
        sx0[2 * i + 1] = v.z; sx1[2 * i + 1] = v.w;
    }
    const float4* mp = (const float4*)(mask + (size_t)b * P + (size_t)chunk * CHUNK);
    #pragma unroll
    for (int i = tid; i < CHUNK / 4; i += BLOCK) {   // 256 float4 = 1024 floats
        float4 v = mp[i];
        smk[4 * i]     = v.x; smk[4 * i + 1] = v.y;
        smk[4 * i + 2] = v.z; smk[4 * i + 3] = v.w;
    }

    // ---- per-lane center coefficients (lane = n) ----
    const int lane = tid & 63;
    const float c0 = centers[2 * lane], c1 = centers[2 * lane + 1];
    const float s0 = sharp[2 * lane],  s1 = sharp[2 * lane + 1];
    const float L  = 1.4426950408889634f;     // log2(e)
    const float C0 = -L * s0, C1 = -L * s1;
    const float B0 = -2.0f * C0 * c0, B1 = -2.0f * C1 * c1;
    const float A  = C0 * c0 * c0 + C1 * c1 * c1;
    // t = A + x0*(C0*x0 + B0) + x1*(C1*x1 + B1)  ==  -log2e * expo

    __syncthreads();

    // ---- main loop: each wave sweeps its 256 points, all lanes same point ----
    const int wave = tid >> 6;
    const int p0   = wave * WPTS;
    float acc0 = 0.f, acc1 = 0.f, acc2 = 0.f, acc3 = 0.f;
    for (int p = p0; p < p0 + WPTS; p += 4) {
        float xa = sx0[p + 0], ya = sx1[p + 0], ma = smk[p + 0];
        float xb = sx0[p + 1], yb = sx1[p + 1], mb = smk[p + 1];
        float xc = sx0[p + 2], yc = sx1[p + 2], mc = smk[p + 2];
        float xd = sx0[p + 3], yd = sx1[p + 3], md = smk[p + 3];
        float ta = fmaf(xa, fmaf(C0, xa, B0), fmaf(ya, fmaf(C1, ya, B1), A));
        float tb = fmaf(xb, fmaf(C0, xb, B0), fmaf(yb, fmaf(C1, yb, B1), A));
        float tc = fmaf(xc, fmaf(C0, xc, B0), fmaf(yc, fmaf(C1, yc, B1), A));
        float td = fmaf(xd, fmaf(C0, xd, B0), fmaf(yd, fmaf(C1, yd, B1), A));
        acc0 = fmaf(ma, EXP2(ta), acc0);
        acc1 = fmaf(mb, EXP2(tb), acc1);
        acc2 = fmaf(mc, EXP2(tc), acc2);
        acc3 = fmaf(md, EXP2(td), acc3);
    }
    float acc = (acc0 + acc1) + (acc2 + acc3);

    // ---- epilogue: reduce 4 waves, one atomicAdd per (b,n) ----
    red[wave][lane] = acc;
    __syncthreads();
    if (tid < N) {
        float s = red[0][tid] + red[1][tid] + red[2][tid] + red[3][tid];
        atomicAdd(&out[b * N + tid], s);
    }
}

extern "C" void kernel_launch(void* const* d_in, const int* in_sizes, int n_in,
                              void* d_out, int out_size, void* d_ws, size_t ws_size,
                              hipStream_t stream) {
    const float* batch   = (const float*)d_in[0];
    const float* mask    = (const float*)d_in[1];
    const float* centers = (const float*)d_in[2];
    const float* sharp   = (const float*)d_in[3];
    float* out = (float*)d_out;

    // d_out is poisoned 0xAA before every call; zero it for the atomic adds.
    hipMemsetAsync(out, 0, (size_t)out_size * sizeof(float), stream);
    slayer_rbf<<<BATCH * CHUNKS, BLOCK, 0, stream>>>(batch, mask, centers, sharp, out);
}